// Round 2
// baseline (2208.780 us; speedup 1.0000x reference)
//
#include <hip/hip_runtime.h>
#include <stdint.h>

// CfC RNN: B=256, T=1024, I=64, U=256, O=64, BB=128. All I/O float32.
// Mapping: 1 workgroup per batch row (recurrence independent per row),
// 512 threads/WG, T-loop inside kernel, h in LDS, all weights in VGPRs
// packed as f16 pairs, inner products via v_dot2_f32_f16 (fp32 accumulate).
#define B_ 256
#define T_ 1024
#define I_ 64
#define U_ 256
#define O_ 64
#define BB_ 128

typedef unsigned int u32;
typedef _Float16 half2_t __attribute__((ext_vector_type(2)));

#if defined(__has_builtin)
#if __has_builtin(__builtin_amdgcn_fdot2)
#define USE_DOT2 1
#else
#define USE_DOT2 0
#endif
#else
#define USE_DOT2 0
#endif

static __device__ __forceinline__ u32 packpair(float a, float b) {
  half2_t h; h.x = (_Float16)a; h.y = (_Float16)b;
  return __builtin_bit_cast(u32, h);
}
static __device__ __forceinline__ float unpack_lo(u32 u) {
  half2_t h = __builtin_bit_cast(half2_t, u); return (float)h.x;
}
static __device__ __forceinline__ float unpack_hi(u32 u) {
  half2_t h = __builtin_bit_cast(half2_t, u); return (float)h.y;
}
static __device__ __forceinline__ float dot2acc(u32 w, u32 z, float acc) {
#if USE_DOT2
  return __builtin_amdgcn_fdot2(__builtin_bit_cast(half2_t, w),
                                __builtin_bit_cast(half2_t, z), acc, false);
#else
  half2_t hw = __builtin_bit_cast(half2_t, w);
  half2_t hz = __builtin_bit_cast(half2_t, z);
  acc += (float)hw.x * (float)hz.x;
  acc += (float)hw.y * (float)hz.y;
  return acc;
#endif
}

// NaN-free saturating tanh/sigmoid (exp overflow -> inf -> correct limit)
static __device__ __forceinline__ float fast_tanh(float x) {
  return 1.0f - 2.0f / (1.0f + __expf(2.0f * x));
}
static __device__ __forceinline__ float fast_sigmoid(float x) {
  return 1.0f / (1.0f + __expf(-x));
}

__global__ __launch_bounds__(512, 2)
void cfc_kernel(const float* __restrict__ x,
                const float* __restrict__ W_bb, const float* __restrict__ b_bb,
                const float* __restrict__ W_ff1, const float* __restrict__ b_ff1,
                const float* __restrict__ W_ff2, const float* __restrict__ b_ff2,
                const float* __restrict__ W_ta,  const float* __restrict__ b_ta,
                const float* __restrict__ W_tb,  const float* __restrict__ b_tb,
                const float* __restrict__ W_fc,  const float* __restrict__ b_fc,
                float* __restrict__ out)
{
  // z = [x_t | h] as packed f16 pairs: s_z2[0..31]=x, s_z2[32..159]=h
  __shared__ __align__(16) u32  s_z2[160];
  __shared__ __align__(16) u32  s_g2[64];
  __shared__ __align__(16) float s_u[1024];   // [ff1 | ff2 | ta | tb] raw+bias
  __shared__ __align__(16) float s_p[512];    // partial sums (stage A and D)

  const int tid = threadIdx.x;
  const int r = blockIdx.x;

  // ---------------- one-time: weights -> registers (packed pairs over K) ----
  // Stage A (backbone [320,128]): col ca = tid&127, K-segment kga*80..+79
  const int ca = tid & 127;
  const int kga = tid >> 7;
  u32 wbb[40];
#pragma unroll
  for (int i = 0; i < 40; ++i) {
    int k = kga * 80 + 2 * i;
    wbb[i] = packpair(W_bb[k * BB_ + ca], W_bb[(k + 1) * BB_ + ca]);
  }
  // Stage B (ff-cat [128,1024]): thread owns cat-cols tid and tid+512
  const int jb = tid & 255;
  const float* MA = (tid < 256) ? W_ff1 : W_ff2;
  const float* MB = (tid < 256) ? W_ta : W_tb;
  u32 wff[128];
#pragma unroll
  for (int i = 0; i < 64; ++i) {
    wff[i]      = packpair(MA[(2 * i) * U_ + jb], MA[(2 * i + 1) * U_ + jb]);
    wff[64 + i] = packpair(MB[(2 * i) * U_ + jb], MB[(2 * i + 1) * U_ + jb]);
  }
  // Stage D (readout [256,64]): col cd = tid&63, K-segment kgd*32..+31
  const int cd = tid & 63;
  const int kgd = tid >> 6;
  u32 wfc[16];
#pragma unroll
  for (int i = 0; i < 16; ++i) {
    int k = kgd * 32 + 2 * i;
    wfc[i] = packpair(W_fc[k * O_ + cd], W_fc[(k + 1) * O_ + cd]);
  }
  // biases (kept f32)
  const float bias0 = (tid < 256) ? b_ff1[jb] : b_ff2[jb];
  const float bias1 = (tid < 256) ? b_ta[jb] : b_tb[jb];
  float bbb0 = 0.f, bbb1 = 0.f, bfcr = 0.f;
  if (tid < 64) {
    bbb0 = b_bb[2 * tid];
    bbb1 = b_bb[2 * tid + 1];
    bfcr = b_fc[tid];
  }

  // h0 = 0
  if (tid < 128) s_z2[32 + tid] = 0u;

  const float* xrow = x + (size_t)r * T_ * I_;
  const size_t out_row = (size_t)r * T_ * O_;

  for (int t = 0; t < T_; ++t) {
    // S1: stage x_t (32 lanes, 2 f32 -> 1 packed pair per lane)
    if (tid < 32) {
      float2 xv = ((const float2*)(xrow + t * I_))[tid];
      s_z2[tid] = packpair(xv.x, xv.y);
    }
    __syncthreads();

    // S2: backbone partial matvec (80 MACs -> 40 dot2 per thread)
    {
      const uint4* z4 = reinterpret_cast<const uint4*>(s_z2 + kga * 40);
      float acc = 0.f;
#pragma unroll
      for (int i = 0; i < 10; ++i) {
        uint4 zz = z4[i];
        acc = dot2acc(wbb[4 * i + 0], zz.x, acc);
        acc = dot2acc(wbb[4 * i + 1], zz.y, acc);
        acc = dot2acc(wbb[4 * i + 2], zz.z, acc);
        acc = dot2acc(wbb[4 * i + 3], zz.w, acc);
      }
      s_p[tid] = acc;
    }
    __syncthreads();

    // S3: reduce 4 partials + lecun_tanh -> g (packed pairs)
    if (tid < 64) {
      int j0 = 2 * tid;
      float v0 = s_p[j0] + s_p[j0 + 128] + s_p[j0 + 256] + s_p[j0 + 384] + bbb0;
      float v1 = s_p[j0 + 1] + s_p[j0 + 129] + s_p[j0 + 257] + s_p[j0 + 385] + bbb1;
      float g0 = 1.7159f * fast_tanh(0.666f * v0);
      float g1 = 1.7159f * fast_tanh(0.666f * v1);
      s_g2[tid] = packpair(g0, g1);
    }
    __syncthreads();

    // S4: fused ff1/ff2/ta/tb matvec: 2 cat-cols per thread, K=128
    {
      const uint4* g4 = reinterpret_cast<const uint4*>(s_g2);
      float a0 = bias0, a1 = bias1;
#pragma unroll
      for (int i = 0; i < 16; ++i) {
        uint4 gg = g4[i];
        a0 = dot2acc(wff[4 * i + 0], gg.x, a0);
        a0 = dot2acc(wff[4 * i + 1], gg.y, a0);
        a0 = dot2acc(wff[4 * i + 2], gg.z, a0);
        a0 = dot2acc(wff[4 * i + 3], gg.w, a0);
        a1 = dot2acc(wff[64 + 4 * i + 0], gg.x, a1);
        a1 = dot2acc(wff[64 + 4 * i + 1], gg.y, a1);
        a1 = dot2acc(wff[64 + 4 * i + 2], gg.z, a1);
        a1 = dot2acc(wff[64 + 4 * i + 3], gg.w, a1);
      }
      s_u[tid] = a0;         // cols 0..511    = [ff1 | ff2]
      s_u[512 + tid] = a1;   // cols 512..1023 = [ta  | tb ]
    }
    __syncthreads();

    // S5: gates -> h_new (2 units per thread), write packed h into z
    if (tid < 128) {
      int j0 = 2 * tid;
      float2 uu1 = *(const float2*)(s_u + j0);
      float2 uu2 = *(const float2*)(s_u + 256 + j0);
      float2 uta = *(const float2*)(s_u + 512 + j0);
      float2 utb = *(const float2*)(s_u + 768 + j0);
      float f1a = fast_tanh(uu1.x), f1b = fast_tanh(uu1.y);
      float f2a = fast_tanh(uu2.x), f2b = fast_tanh(uu2.y);
      float tia = fast_sigmoid(uta.x + utb.x);
      float tib = fast_sigmoid(uta.y + utb.y);
      float ha = f1a + tia * (f2a - f1a);
      float hb = f1b + tib * (f2b - f1b);
      s_z2[32 + tid] = packpair(ha, hb);
    }
    __syncthreads();

    // S6: readout partial matvec (32 MACs -> 16 dot2 per thread)
    {
      const uint4* h4 = reinterpret_cast<const uint4*>(s_z2 + 32 + kgd * 16);
      float acc = 0.f;
#pragma unroll
      for (int i = 0; i < 4; ++i) {
        uint4 hh = h4[i];
        acc = dot2acc(wfc[4 * i + 0], hh.x, acc);
        acc = dot2acc(wfc[4 * i + 1], hh.y, acc);
        acc = dot2acc(wfc[4 * i + 2], hh.z, acc);
        acc = dot2acc(wfc[4 * i + 3], hh.w, acc);
      }
      s_p[tid] = acc;
    }
    __syncthreads();

    // S7: reduce 8 partials + bias, store out[r, t, :] (f32)
    if (tid < 64) {
      float o = bfcr;
#pragma unroll
      for (int i = 0; i < 8; ++i) o += s_p[tid + 64 * i];
      out[out_row + (size_t)t * O_ + tid] = o;
    }
    // next-iteration S1 __syncthreads() orders s_p / s_z2 reuse
  }

  __syncthreads();
  // h_last -> d_out tail (element offset B*T*O), 2 f32 per lane
  if (tid < 128) {
    u32 hp = s_z2[32 + tid];
    float2 hv; hv.x = unpack_lo(hp); hv.y = unpack_hi(hp);
    ((float2*)(out + (size_t)B_ * T_ * O_))[r * 128 + tid] = hv;
  }
}

extern "C" void kernel_launch(void* const* d_in, const int* in_sizes, int n_in,
                              void* d_out, int out_size, void* d_ws, size_t ws_size,
                              hipStream_t stream) {
  const float* x     = (const float*)d_in[0];
  const float* W_bb  = (const float*)d_in[1];
  const float* b_bb  = (const float*)d_in[2];
  const float* W_ff1 = (const float*)d_in[3];
  const float* b_ff1 = (const float*)d_in[4];
  const float* W_ff2 = (const float*)d_in[5];
  const float* b_ff2 = (const float*)d_in[6];
  const float* W_ta  = (const float*)d_in[7];
  const float* b_ta  = (const float*)d_in[8];
  const float* W_tb  = (const float*)d_in[9];
  const float* b_tb  = (const float*)d_in[10];
  const float* W_fc  = (const float*)d_in[11];
  const float* b_fc  = (const float*)d_in[12];
  float* out = (float*)d_out;

  cfc_kernel<<<dim3(B_), dim3(512), 0, stream>>>(
      x, W_bb, b_bb, W_ff1, b_ff1, W_ff2, b_ff2,
      W_ta, b_ta, W_tb, b_tb, W_fc, b_fc, out);
}

// Round 3
// 2140.518 us; speedup vs baseline: 1.0319x; 1.0319x over previous
//
#include <hip/hip_runtime.h>
#include <stdint.h>

// CfC RNN: B=256, T=1024, I=64, U=256, O=64, BB=128. All I/O float32.
// One WG (512 thr) per batch row, T-loop in-kernel, weights in registers as
// f16 pairs (v_dot2_f32_f16, fp32 acc). TWO barriers per step:
//   Phase A: backbone matvec (shfl-reduced) + readout of h_{t-1} (shfl-reduced)
//   Phase B: fused ff1/ff2/ta/tb matvec + gates -> h_t ; stage x_{t+1}
#define B_ 256
#define T_ 1024
#define I_ 64
#define U_ 256
#define O_ 64
#define BB_ 128

typedef unsigned int u32;
typedef _Float16 half2_t __attribute__((ext_vector_type(2)));

#if defined(__has_builtin)
#if __has_builtin(__builtin_amdgcn_fdot2)
#define USE_DOT2 1
#else
#define USE_DOT2 0
#endif
#else
#define USE_DOT2 0
#endif

static __device__ __forceinline__ u32 packpair(float a, float b) {
  half2_t h; h.x = (_Float16)a; h.y = (_Float16)b;
  return __builtin_bit_cast(u32, h);
}
static __device__ __forceinline__ float unpack_lo(u32 u) {
  half2_t h = __builtin_bit_cast(half2_t, u); return (float)h.x;
}
static __device__ __forceinline__ float unpack_hi(u32 u) {
  half2_t h = __builtin_bit_cast(half2_t, u); return (float)h.y;
}
static __device__ __forceinline__ float dot2acc(u32 w, u32 z, float acc) {
#if USE_DOT2
  return __builtin_amdgcn_fdot2(__builtin_bit_cast(half2_t, w),
                                __builtin_bit_cast(half2_t, z), acc, false);
#else
  half2_t hw = __builtin_bit_cast(half2_t, w);
  half2_t hz = __builtin_bit_cast(half2_t, z);
  acc += (float)hw.x * (float)hz.x;
  acc += (float)hw.y * (float)hz.y;
  return acc;
#endif
}

// NaN-free saturating tanh/sigmoid (exp overflow -> inf -> correct limit)
static __device__ __forceinline__ float fast_tanh(float x) {
  return 1.0f - 2.0f / (1.0f + __expf(2.0f * x));
}
static __device__ __forceinline__ float fast_sigmoid(float x) {
  return 1.0f / (1.0f + __expf(-x));
}

__global__ __launch_bounds__(512, 2)
void cfc_kernel(const float* __restrict__ x,
                const float* __restrict__ W_bb, const float* __restrict__ b_bb,
                const float* __restrict__ W_ff1, const float* __restrict__ b_ff1,
                const float* __restrict__ W_ff2, const float* __restrict__ b_ff2,
                const float* __restrict__ W_ta,  const float* __restrict__ b_ta,
                const float* __restrict__ W_tb,  const float* __restrict__ b_tb,
                const float* __restrict__ W_fc,  const float* __restrict__ b_fc,
                float* __restrict__ out)
{
  // z = [x_t | h_t] as packed f16 pairs: s_z2[0..31]=x (32 pairs),
  // s_z2[32..159]=h (128 pairs).  g: 64 packed pairs.
  __shared__ __align__(16) u32 s_z2[160];
  __shared__ __align__(16) u32 s_g2[64];

  const int tid  = threadIdx.x;
  const int lane = tid & 63;
  const int r    = blockIdx.x;

  // ---- thread mappings ----
  // Phase A backbone: col ca=tid>>2 (0..127), K-quarter kga=tid&3 (40 pairs)
  const int ca  = tid >> 2;
  const int kga = tid & 3;
  // Phase A readout: wave wv, output ro (0..63), K-eighth rk (16 pairs)
  const int wv = tid >> 6;
  const int ro = 8 * wv + (lane >> 3);
  const int rk = lane & 7;
  // Phase B: unit jb=tid>>1 (0..255), K-half kh=tid&1 (32 pairs)
  const int jb = tid >> 1;
  const int kh = tid & 1;

  // ---- one-time: weights -> registers (f16 pairs along K) ----
  u32 wbb[40];
#pragma unroll
  for (int i = 0; i < 40; ++i) {
    int p = 40 * kga + i;
    wbb[i] = packpair(W_bb[(2 * p) * BB_ + ca], W_bb[(2 * p + 1) * BB_ + ca]);
  }
  u32 wfc[16];
#pragma unroll
  for (int i = 0; i < 16; ++i) {
    int p = 16 * rk + i;
    wfc[i] = packpair(W_fc[(2 * p) * O_ + ro], W_fc[(2 * p + 1) * O_ + ro]);
  }
  u32 wf1[32], wf2[32], wta[32], wtb[32];
#pragma unroll
  for (int i = 0; i < 32; ++i) {
    int p = 32 * kh + i;
    int k0 = 2 * p, k1 = 2 * p + 1;
    wf1[i] = packpair(W_ff1[k0 * U_ + jb], W_ff1[k1 * U_ + jb]);
    wf2[i] = packpair(W_ff2[k0 * U_ + jb], W_ff2[k1 * U_ + jb]);
    wta[i] = packpair(W_ta [k0 * U_ + jb], W_ta [k1 * U_ + jb]);
    wtb[i] = packpair(W_tb [k0 * U_ + jb], W_tb [k1 * U_ + jb]);
  }
  const float bbbc = b_bb[ca];
  const float bfo  = b_fc[ro];
  const float b1 = b_ff1[jb], b2 = b_ff2[jb];
  const float bta = b_ta[jb], btb = b_tb[jb];

  const float* xrow = x + (size_t)r * T_ * I_;
  const size_t out_row = (size_t)r * T_ * O_;

  // ---- init: h0 = 0, stage x_0 ----
  if (tid < 128) s_z2[32 + tid] = 0u;
  if (tid < 32) {
    float2 xv = ((const float2*)xrow)[tid];
    s_z2[tid] = packpair(xv.x, xv.y);
  }
  __syncthreads();

  for (int t = 0; t < T_; ++t) {
    // ================= Phase A =================
    // backbone: 40 dot2 over z-slice [40*kga, 40*kga+40)
    float bacc = 0.f;
    {
      const uint4* z4 = reinterpret_cast<const uint4*>(s_z2 + 40 * kga);
#pragma unroll
      for (int i = 0; i < 10; ++i) {
        uint4 zz = z4[i];
        bacc = dot2acc(wbb[4 * i + 0], zz.x, bacc);
        bacc = dot2acc(wbb[4 * i + 1], zz.y, bacc);
        bacc = dot2acc(wbb[4 * i + 2], zz.z, bacc);
        bacc = dot2acc(wbb[4 * i + 3], zz.w, bacc);
      }
    }
    // readout of h_{t-1}: 16 dot2 over h-slice [16*rk, 16*rk+16)
    float racc = 0.f;
    {
      const uint4* h4 = reinterpret_cast<const uint4*>(s_z2 + 32 + 16 * rk);
#pragma unroll
      for (int i = 0; i < 4; ++i) {
        uint4 hh = h4[i];
        racc = dot2acc(wfc[4 * i + 0], hh.x, racc);
        racc = dot2acc(wfc[4 * i + 1], hh.y, racc);
        racc = dot2acc(wfc[4 * i + 2], hh.z, racc);
        racc = dot2acc(wfc[4 * i + 3], hh.w, racc);
      }
    }
    // butterfly reduce backbone partials across kga lanes (quad)
    bacc += __shfl_xor(bacc, 1);
    bacc += __shfl_xor(bacc, 2);
    float g = 1.7159f * fast_tanh(0.666f * (bacc + bbbc));
    float gn = __shfl_down(g, 4);   // g[ca+1] lives 4 lanes up
    // butterfly reduce readout partials across rk lanes (octet)
    racc += __shfl_xor(racc, 1);
    racc += __shfl_xor(racc, 2);
    racc += __shfl_xor(racc, 4);

    if ((tid & 7) == 0) s_g2[tid >> 3] = packpair(g, gn);
    if (t > 0 && rk == 0)
      out[out_row + (size_t)(t - 1) * O_ + ro] = racc + bfo;
    __syncthreads();

    // ================= Phase B =================
    // prefetch x_{t+1} (latency hidden under the 128 dot2s below)
    float2 xv;
    const bool ldx = (tid < 32) && (t + 1 < T_);
    if (ldx) xv = ((const float2*)(xrow + (size_t)(t + 1) * I_))[tid];

    float a1 = 0.f, a2 = 0.f, a3 = 0.f, a4 = 0.f;
    {
      const uint4* g4 = reinterpret_cast<const uint4*>(s_g2 + 32 * kh);
#pragma unroll
      for (int i = 0; i < 8; ++i) {
        uint4 gg = g4[i];
        a1 = dot2acc(wf1[4 * i + 0], gg.x, a1);
        a1 = dot2acc(wf1[4 * i + 1], gg.y, a1);
        a1 = dot2acc(wf1[4 * i + 2], gg.z, a1);
        a1 = dot2acc(wf1[4 * i + 3], gg.w, a1);
        a2 = dot2acc(wf2[4 * i + 0], gg.x, a2);
        a2 = dot2acc(wf2[4 * i + 1], gg.y, a2);
        a2 = dot2acc(wf2[4 * i + 2], gg.z, a2);
        a2 = dot2acc(wf2[4 * i + 3], gg.w, a2);
        a3 = dot2acc(wta[4 * i + 0], gg.x, a3);
        a3 = dot2acc(wta[4 * i + 1], gg.y, a3);
        a3 = dot2acc(wta[4 * i + 2], gg.z, a3);
        a3 = dot2acc(wta[4 * i + 3], gg.w, a3);
        a4 = dot2acc(wtb[4 * i + 0], gg.x, a4);
        a4 = dot2acc(wtb[4 * i + 1], gg.y, a4);
        a4 = dot2acc(wtb[4 * i + 2], gg.z, a4);
        a4 = dot2acc(wtb[4 * i + 3], gg.w, a4);
      }
    }
    // complete the K-split: both lanes of the pair end with full sums
    a1 += __shfl_xor(a1, 1);
    a2 += __shfl_xor(a2, 1);
    a3 += __shfl_xor(a3, 1);
    a4 += __shfl_xor(a4, 1);
    float f1 = fast_tanh(a1 + b1);
    float f2 = fast_tanh(a2 + b2);
    float ti = fast_sigmoid(a3 + bta + a4 + btb);
    float h  = f1 + ti * (f2 - f1);
    float hn = __shfl_down(h, 2);   // h[jb+1] lives 2 lanes up

    if (ldx) s_z2[tid] = packpair(xv.x, xv.y);
    if ((tid & 3) == 0) s_z2[32 + (tid >> 2)] = packpair(h, hn);
    __syncthreads();
  }

  // ---- final readout: h_{T-1} -> out[:, T-1, :] ----
  {
    float racc = 0.f;
    const uint4* h4 = reinterpret_cast<const uint4*>(s_z2 + 32 + 16 * rk);
#pragma unroll
    for (int i = 0; i < 4; ++i) {
      uint4 hh = h4[i];
      racc = dot2acc(wfc[4 * i + 0], hh.x, racc);
      racc = dot2acc(wfc[4 * i + 1], hh.y, racc);
      racc = dot2acc(wfc[4 * i + 2], hh.z, racc);
      racc = dot2acc(wfc[4 * i + 3], hh.w, racc);
    }
    racc += __shfl_xor(racc, 1);
    racc += __shfl_xor(racc, 2);
    racc += __shfl_xor(racc, 4);
    if (rk == 0)
      out[out_row + (size_t)(T_ - 1) * O_ + ro] = racc + bfo;
  }

  // ---- h_last -> d_out tail (element offset B*T*O) ----
  if (tid < 128) {
    u32 hp = s_z2[32 + tid];
    float2 hv; hv.x = unpack_lo(hp); hv.y = unpack_hi(hp);
    ((float2*)(out + (size_t)B_ * T_ * O_))[r * 128 + tid] = hv;
  }
}

extern "C" void kernel_launch(void* const* d_in, const int* in_sizes, int n_in,
                              void* d_out, int out_size, void* d_ws, size_t ws_size,
                              hipStream_t stream) {
  const float* x     = (const float*)d_in[0];
  const float* W_bb  = (const float*)d_in[1];
  const float* b_bb  = (const float*)d_in[2];
  const float* W_ff1 = (const float*)d_in[3];
  const float* b_ff1 = (const float*)d_in[4];
  const float* W_ff2 = (const float*)d_in[5];
  const float* b_ff2 = (const float*)d_in[6];
  const float* W_ta  = (const float*)d_in[7];
  const float* b_ta  = (const float*)d_in[8];
  const float* W_tb  = (const float*)d_in[9];
  const float* b_tb  = (const float*)d_in[10];
  const float* W_fc  = (const float*)d_in[11];
  const float* b_fc  = (const float*)d_in[12];
  float* out = (float*)d_out;

  cfc_kernel<<<dim3(B_), dim3(512), 0, stream>>>(
      x, W_bb, b_bb, W_ff1, b_ff1, W_ff2, b_ff2,
      W_ta, b_ta, W_tb, b_tb, W_fc, b_fc, out);
}

// Round 5
// 1903.363 us; speedup vs baseline: 1.1605x; 1.1246x over previous
//
#include <hip/hip_runtime.h>
#include <stdint.h>

// CfC RNN: B=256, T=1024, I=64, U=256, O=64, BB=128. All I/O float32.
// One WG (1024 thr, 16 waves) per batch row, T-loop in-kernel, weights in
// VGPRs as f16 pairs (v_dot2_f32_f16, fp32 acc). Cross-lane reductions via
// palindromic DPP only (quad_perm xor, row_half_mirror, row_mirror) -- no
// direction-sensitive shifts. Readout GEMM deferred to a second kernel via
// an f16 H buffer in d_ws (fallback: in-loop readout).
#define B_ 256
#define T_ 1024
#define I_ 64
#define U_ 256
#define O_ 64
#define BB_ 128

typedef unsigned int u32;
typedef unsigned short u16;
typedef _Float16 half2_t __attribute__((ext_vector_type(2)));

#if defined(__has_builtin)
#if __has_builtin(__builtin_amdgcn_fdot2)
#define USE_DOT2 1
#else
#define USE_DOT2 0
#endif
#else
#define USE_DOT2 0
#endif

static __device__ __forceinline__ u32 packpair(float a, float b) {
  half2_t h; h.x = (_Float16)a; h.y = (_Float16)b;
  return __builtin_bit_cast(u32, h);
}
static __device__ __forceinline__ float unpack_lo(u32 u) {
  half2_t h = __builtin_bit_cast(half2_t, u); return (float)h.x;
}
static __device__ __forceinline__ float unpack_hi(u32 u) {
  half2_t h = __builtin_bit_cast(half2_t, u); return (float)h.y;
}
static __device__ __forceinline__ float dot2acc(u32 w, u32 z, float acc) {
#if USE_DOT2
  return __builtin_amdgcn_fdot2(__builtin_bit_cast(half2_t, w),
                                __builtin_bit_cast(half2_t, z), acc, false);
#else
  half2_t hw = __builtin_bit_cast(half2_t, w);
  half2_t hz = __builtin_bit_cast(half2_t, z);
  acc += (float)hw.x * (float)hz.x;
  acc += (float)hw.y * (float)hz.y;
  return acc;
#endif
}

// DPP cross-lane moves (VALU pipe; no LDS). ONLY palindromic (self-inverse)
// controls -- immune to shift-direction convention:
//   quad_perm xor1 = 0xB1 [1,0,3,2], xor2 = 0x4E [2,3,0,1]
//   row_half_mirror = 0x141 (lane i <-> i^7 within each 8-lane half-row)
//   row_mirror      = 0x140 (lane i <-> 15-i within each 16-lane row)
template <int CTRL>
static __device__ __forceinline__ float dpp_mov_f(float v) {
  return __builtin_bit_cast(float, __builtin_amdgcn_update_dpp(
      0, __builtin_bit_cast(int, v), CTRL, 0xF, 0xF, true));
}
#define DPP_XOR1 0xB1
#define DPP_XOR2 0x4E
#define DPP_HMIR 0x141
#define DPP_MIRR 0x140

// NaN-free saturating tanh/sigmoid (exp overflow -> inf -> correct limit)
static __device__ __forceinline__ float fast_tanh(float x) {
  return 1.0f - 2.0f / (1.0f + __expf(2.0f * x));
}
static __device__ __forceinline__ float fast_sigmoid(float x) {
  return 1.0f / (1.0f + __expf(-x));
}

template <bool DEFER>
__global__ __launch_bounds__(1024)
void cfc_kernel(const float* __restrict__ x,
                const float* __restrict__ W_bb, const float* __restrict__ b_bb,
                const float* __restrict__ W_ff1, const float* __restrict__ b_ff1,
                const float* __restrict__ W_ff2, const float* __restrict__ b_ff2,
                const float* __restrict__ W_ta,  const float* __restrict__ b_ta,
                const float* __restrict__ W_tb,  const float* __restrict__ b_tb,
                const float* __restrict__ W_fc,  const float* __restrict__ b_fc,
                float* __restrict__ out, u32* __restrict__ Hbuf)
{
  // z = [x_t | h_t] as packed f16 pairs: s_z2[0..31]=x, s_z2[32..159]=h.
  __shared__ __align__(16) u32 s_z2[160];
  __shared__ __align__(16) u32 s_g2[64];
  u16* s_gh = (u16*)s_g2;

  const int tid = threadIdx.x;
  const int r   = blockIdx.x;

  // ---- thread mappings ----
  // Phase A backbone: col ca=tid>>3 (0..127), K-eighth kga=tid&7.
  //   K ownership interleaved in 16B groups: pair-groups {kga+8j, j=0..4}.
  const int ca  = tid >> 3;
  const int kga = tid & 7;
  // Phase B ff: unit jb=tid>>2 (0..255), K-quarter kq=tid&3,
  //   pair-groups {kq+4j, j=0..3}.
  const int jb = tid >> 2;
  const int kq = tid & 3;
  // Fallback readout: output ro=tid>>4 (0..63), K-16th rk=tid&15,
  //   pair-groups {rk+16j, j=0..1}.
  const int ro = tid >> 4;
  const int rk = tid & 15;

  // ---- one-time: weights -> registers (f16 pairs along K) ----
  u32 wbb[20];
#pragma unroll
  for (int j = 0; j < 5; ++j)
#pragma unroll
    for (int q = 0; q < 4; ++q) {
      int p = 4 * (kga + 8 * j) + q;
      wbb[4 * j + q] = packpair(W_bb[(2 * p) * BB_ + ca],
                                W_bb[(2 * p + 1) * BB_ + ca]);
    }
  u32 wf1[16], wf2[16], wta[16], wtb[16];
#pragma unroll
  for (int j = 0; j < 4; ++j)
#pragma unroll
    for (int q = 0; q < 4; ++q) {
      int p = 4 * (kq + 4 * j) + q;
      int k0 = 2 * p, k1 = 2 * p + 1;
      wf1[4 * j + q] = packpair(W_ff1[k0 * U_ + jb], W_ff1[k1 * U_ + jb]);
      wf2[4 * j + q] = packpair(W_ff2[k0 * U_ + jb], W_ff2[k1 * U_ + jb]);
      wta[4 * j + q] = packpair(W_ta [k0 * U_ + jb], W_ta [k1 * U_ + jb]);
      wtb[4 * j + q] = packpair(W_tb [k0 * U_ + jb], W_tb [k1 * U_ + jb]);
    }
  u32 wfc[8];
  float bfo = 0.f;
  if (!DEFER) {
#pragma unroll
    for (int j = 0; j < 2; ++j)
#pragma unroll
      for (int q = 0; q < 4; ++q) {
        int p = 4 * (rk + 16 * j) + q;
        wfc[4 * j + q] = packpair(W_fc[(2 * p) * O_ + ro],
                                  W_fc[(2 * p + 1) * O_ + ro]);
      }
    bfo = b_fc[ro];
  }
  const float bbbc = b_bb[ca];
  const float b1 = b_ff1[jb], b2 = b_ff2[jb];
  const float bta = b_ta[jb], btb = b_tb[jb];

  const float* xrow = x + (size_t)r * T_ * I_;
  const size_t out_row = (size_t)r * T_ * O_;
  u32* __restrict__ hrow = DEFER ? (Hbuf + (size_t)r * T_ * (U_ / 2)) : nullptr;

  // ---- init: h0 = 0, stage x_0 ----
  if (tid < 160) s_z2[tid] = 0u;
  __syncthreads();
  if (tid < 32) {
    float2 xv = ((const float2*)xrow)[tid];
    s_z2[tid] = packpair(xv.x, xv.y);
  }
  __syncthreads();

  for (int t = 0; t < T_; ++t) {
    // prefetch x_{t+1} early (consumed end of Phase B)
    float2 xv;
    const bool ldx = (tid < 32) && (t + 1 < T_);
    if (ldx) xv = ((const float2*)(xrow + (size_t)(t + 1) * I_))[tid];

    // ================= Phase A: backbone =================
    float bacc = 0.f;
#pragma unroll
    for (int j = 0; j < 5; ++j) {
      uint4 zz = *reinterpret_cast<const uint4*>(s_z2 + 4 * (kga + 8 * j));
      bacc = dot2acc(wbb[4 * j + 0], zz.x, bacc);
      bacc = dot2acc(wbb[4 * j + 1], zz.y, bacc);
      bacc = dot2acc(wbb[4 * j + 2], zz.z, bacc);
      bacc = dot2acc(wbb[4 * j + 3], zz.w, bacc);
    }
    // reduce over the 8 kga lanes (consecutive): quad xor1+xor2 -> quad
    // sums on all 4 lanes; half_mirror (i^7) crosses to the partner quad
    // within the 8-group -> full sum on all 8 lanes.
    bacc += dpp_mov_f<DPP_XOR1>(bacc);
    bacc += dpp_mov_f<DPP_XOR2>(bacc);
    bacc += dpp_mov_f<DPP_HMIR>(bacc);
    float g = 1.7159f * fast_tanh(0.666f * (bacc + bbbc));

    float racc = 0.f;
    if (!DEFER) {
      // readout of h_{t-1}: 8 dot2 over interleaved h-slices
#pragma unroll
      for (int j = 0; j < 2; ++j) {
        uint4 hh = *reinterpret_cast<const uint4*>(s_z2 + 32 + 4 * (rk + 16 * j));
        racc = dot2acc(wfc[4 * j + 0], hh.x, racc);
        racc = dot2acc(wfc[4 * j + 1], hh.y, racc);
        racc = dot2acc(wfc[4 * j + 2], hh.z, racc);
        racc = dot2acc(wfc[4 * j + 3], hh.w, racc);
      }
      // full 16-lane reduce: quads -> 8-groups (half_mirror) -> row (mirror)
      racc += dpp_mov_f<DPP_XOR1>(racc);
      racc += dpp_mov_f<DPP_XOR2>(racc);
      racc += dpp_mov_f<DPP_HMIR>(racc);
      racc += dpp_mov_f<DPP_MIRR>(racc);
    }
    if ((tid & 7) == 0)
      s_gh[ca] = __builtin_bit_cast(u16, (_Float16)g);
    if (!DEFER && t > 0 && rk == 0)
      out[out_row + (size_t)(t - 1) * O_ + ro] = racc + bfo;
    __syncthreads();

    // ================= Phase B: fused ff1/ff2/ta/tb =================
    float a1 = 0.f, a2 = 0.f, a3 = 0.f, a4 = 0.f;
#pragma unroll
    for (int j = 0; j < 4; ++j) {
      uint4 gg = *reinterpret_cast<const uint4*>(s_g2 + 4 * (kq + 4 * j));
      a1 = dot2acc(wf1[4 * j + 0], gg.x, a1);
      a1 = dot2acc(wf1[4 * j + 1], gg.y, a1);
      a1 = dot2acc(wf1[4 * j + 2], gg.z, a1);
      a1 = dot2acc(wf1[4 * j + 3], gg.w, a1);
      a2 = dot2acc(wf2[4 * j + 0], gg.x, a2);
      a2 = dot2acc(wf2[4 * j + 1], gg.y, a2);
      a2 = dot2acc(wf2[4 * j + 2], gg.z, a2);
      a2 = dot2acc(wf2[4 * j + 3], gg.w, a2);
      a3 = dot2acc(wta[4 * j + 0], gg.x, a3);
      a3 = dot2acc(wta[4 * j + 1], gg.y, a3);
      a3 = dot2acc(wta[4 * j + 2], gg.z, a3);
      a3 = dot2acc(wta[4 * j + 3], gg.w, a3);
      a4 = dot2acc(wtb[4 * j + 0], gg.x, a4);
      a4 = dot2acc(wtb[4 * j + 1], gg.y, a4);
      a4 = dot2acc(wtb[4 * j + 2], gg.z, a4);
      a4 = dot2acc(wtb[4 * j + 3], gg.w, a4);
    }
    // reduce over 4 kq lanes (quad): xor1 + xor2 -> full sum on all 4 lanes
    a1 += dpp_mov_f<DPP_XOR1>(a1); a1 += dpp_mov_f<DPP_XOR2>(a1);
    a2 += dpp_mov_f<DPP_XOR1>(a2); a2 += dpp_mov_f<DPP_XOR2>(a2);
    a3 += dpp_mov_f<DPP_XOR1>(a3); a3 += dpp_mov_f<DPP_XOR2>(a3);
    a4 += dpp_mov_f<DPP_XOR1>(a4); a4 += dpp_mov_f<DPP_XOR2>(a4);
    float f1 = fast_tanh(a1 + b1);
    float f2 = fast_tanh(a2 + b2);
    float ti = fast_sigmoid(a3 + bta + a4 + btb);
    float h  = f1 + ti * (f2 - f1);
    // pair partner: units (2m,2m+1) occupy adjacent quads of an 8-group;
    // half_mirror (i^7) at writer lanes (s=0 reads s=7, s=8 reads s=15)
    // fetches h[jb+1] from the partner quad.
    float hq = dpp_mov_f<DPP_HMIR>(h);

    if ((tid & 7) == 0) {
      u32 pr = packpair(h, hq);
      int m = tid >> 3;               // 0..127
      s_z2[32 + m] = pr;
      if (DEFER) hrow[(size_t)t * (U_ / 2) + m] = pr;
    }
    if (ldx) s_z2[tid] = packpair(xv.x, xv.y);
    __syncthreads();
  }

  if (!DEFER) {
    // final readout: h_{T-1} -> out[:, T-1, :]
    float racc = 0.f;
#pragma unroll
    for (int j = 0; j < 2; ++j) {
      uint4 hh = *reinterpret_cast<const uint4*>(s_z2 + 32 + 4 * (rk + 16 * j));
      racc = dot2acc(wfc[4 * j + 0], hh.x, racc);
      racc = dot2acc(wfc[4 * j + 1], hh.y, racc);
      racc = dot2acc(wfc[4 * j + 2], hh.z, racc);
      racc = dot2acc(wfc[4 * j + 3], hh.w, racc);
    }
    racc += dpp_mov_f<DPP_XOR1>(racc);
    racc += dpp_mov_f<DPP_XOR2>(racc);
    racc += dpp_mov_f<DPP_HMIR>(racc);
    racc += dpp_mov_f<DPP_MIRR>(racc);
    if (rk == 0)
      out[out_row + (size_t)(T_ - 1) * O_ + ro] = racc + bfo;
  }

  // ---- h_last -> d_out tail (element offset B*T*O) ----
  if (tid < 128) {
    u32 hp = s_z2[32 + tid];
    float2 hv; hv.x = unpack_lo(hp); hv.y = unpack_hi(hp);
    ((float2*)(out + (size_t)B_ * T_ * O_))[r * 128 + tid] = hv;
  }
}

// Deferred readout: out[r,t,:] = H[r,t,:] @ W_fc + b_fc.
// Grid 256 (one r per block), 512 threads = 8 waves; wave w handles row
// t = 8c + w of each 8-row chunk staged in LDS.
__global__ __launch_bounds__(512)
void ro_kernel(const u32* __restrict__ Hbuf,
               const float* __restrict__ W_fc, const float* __restrict__ b_fc,
               float* __restrict__ out)
{
  __shared__ __align__(16) u32 s_h[8 * 128];
  const int tid = threadIdx.x;
  const int o   = tid & 63;
  const int w   = tid >> 6;
  const int r   = blockIdx.x;

  u32 wfc[128];
#pragma unroll
  for (int p = 0; p < 128; ++p)
    wfc[p] = packpair(W_fc[(2 * p) * O_ + o], W_fc[(2 * p + 1) * O_ + o]);
  const float bo = b_fc[o];

  const u32* hrow = Hbuf + (size_t)r * T_ * 128;
  const size_t out_row = (size_t)r * T_ * O_;

  for (int c = 0; c < T_ / 8; ++c) {
    // stage 8 rows (1024 u32): each thread loads uint2
    *(uint2*)(s_h + 2 * tid) =
        *(const uint2*)(hrow + (size_t)c * 1024 + 2 * tid);
    __syncthreads();
    float acc = bo;
    const uint4* h4 = reinterpret_cast<const uint4*>(s_h + w * 128);
#pragma unroll
    for (int i = 0; i < 32; ++i) {
      uint4 hh = h4[i];
      acc = dot2acc(wfc[4 * i + 0], hh.x, acc);
      acc = dot2acc(wfc[4 * i + 1], hh.y, acc);
      acc = dot2acc(wfc[4 * i + 2], hh.z, acc);
      acc = dot2acc(wfc[4 * i + 3], hh.w, acc);
    }
    out[out_row + (size_t)(8 * c + w) * O_ + o] = acc;
    __syncthreads();
  }
}

extern "C" void kernel_launch(void* const* d_in, const int* in_sizes, int n_in,
                              void* d_out, int out_size, void* d_ws, size_t ws_size,
                              hipStream_t stream) {
  const float* x     = (const float*)d_in[0];
  const float* W_bb  = (const float*)d_in[1];
  const float* b_bb  = (const float*)d_in[2];
  const float* W_ff1 = (const float*)d_in[3];
  const float* b_ff1 = (const float*)d_in[4];
  const float* W_ff2 = (const float*)d_in[5];
  const float* b_ff2 = (const float*)d_in[6];
  const float* W_ta  = (const float*)d_in[7];
  const float* b_ta  = (const float*)d_in[8];
  const float* W_tb  = (const float*)d_in[9];
  const float* b_tb  = (const float*)d_in[10];
  const float* W_fc  = (const float*)d_in[11];
  const float* b_fc  = (const float*)d_in[12];
  float* out = (float*)d_out;

  const size_t h_bytes = (size_t)B_ * T_ * (U_ / 2) * sizeof(u32);  // 128 MiB
  if (ws_size >= h_bytes) {
    u32* Hbuf = (u32*)d_ws;
    cfc_kernel<true><<<dim3(B_), dim3(1024), 0, stream>>>(
        x, W_bb, b_bb, W_ff1, b_ff1, W_ff2, b_ff2,
        W_ta, b_ta, W_tb, b_tb, W_fc, b_fc, out, Hbuf);
    ro_kernel<<<dim3(B_), dim3(512), 0, stream>>>(Hbuf, W_fc, b_fc, out);
  } else {
    cfc_kernel<false><<<dim3(B_), dim3(1024), 0, stream>>>(
        x, W_bb, b_bb, W_ff1, b_ff1, W_ff2, b_ff2,
        W_ta, b_ta, W_tb, b_tb, W_fc, b_fc, out, nullptr);
  }
}